// Round 4
// baseline (1070.156 us; speedup 1.0000x reference)
//
#include <hip/hip_runtime.h>
#include <hip/hip_bf16.h>

#define NIN 32
#define NHID 128
#define NOUT 16
#define NIN1 160   // NIN+NHID = 160 feature records, K = 160*8 = 1280
#define SEQT 512
#define NB 256

typedef __attribute__((ext_vector_type(8))) short s16x8;   // 8 bf16 (4 VGPRs) - MFMA A/B frag
typedef __attribute__((ext_vector_type(4))) float f32x4;   // MFMA C/D frag

// manual RNE f32->bf16 (inputs are finite/sane here)
__device__ __forceinline__ unsigned int f2bfbits(float f) {
    unsigned int u = __float_as_uint(f);
    return (u + 0x7fffu + ((u >> 16) & 1u)) >> 16;
}
__device__ __forceinline__ unsigned int packbf(float lo, float hi) {
    return f2bfbits(lo) | (f2bfbits(hi) << 16);
}

// Knots: t_m = -8.8 + 1.6*m (G=5, K=3, range [-4,4]); uniform -> closed-form
// cubic basis (verified PASS rounds 1,3).
__device__ __forceinline__ void spline_feat(float c, float* out4, int* jst) {
    const float t0 = -8.8f, inv_h = 0.625f;
    float u  = (c - t0) * inv_h;
    float uf = floorf(u);
    int   m0 = (int)uf;
    bool valid = (m0 >= 0) && (m0 <= 10);
    float f   = u - uf;
    float omf = 1.0f - f;
    float f2 = f * f, f3 = f2 * f;
    float omf3 = omf * omf * omf;
    const float c6 = 0.16666667f;
    float v0 = omf3 * c6;
    float v1 = __builtin_fmaf(3.0f, f3, __builtin_fmaf(-6.0f, f2, 4.0f)) * c6;
    float v2 = __builtin_fmaf(-3.0f, f3, __builtin_fmaf(3.0f, f + f2, 1.0f)) * c6;
    float v3 = f3 * c6;
    float v[4] = {v0, v1, v2, v3};
    int jb = m0 - 3;
    int js = jb < 0 ? 0 : (jb > 4 ? 4 : jb);
    int sh = js - jb;
    #pragma unroll
    for (int r = 0; r < 4; ++r) {
        int rs = r + sh;
        out4[r] = (valid && rs >= 0 && rs <= 3) ? v[rs] : 0.f;
    }
    *jst = js;
}

__device__ __forceinline__ float fsilu(float c) {
    return c * __builtin_amdgcn_rcpf(1.f + __expf(-c));
}

// ---- X-macro lists ----
#define R20(X) X(0) X(1) X(2) X(3) X(4) X(5) X(6) X(7) X(8) X(9) \
               X(10) X(11) X(12) X(13) X(14) X(15) X(16) X(17) X(18) X(19)
#define R10A(X) X(0) X(1) X(2) X(3) X(4) X(5) X(6) X(7) X(8) X(9)
#define R10B(X) X(10) X(11) X(12) X(13) X(14) X(15) X(16) X(17) X(18) X(19)
#define O8(X) X(0) X(1) X(2) X(3) X(4) X(5) X(6) X(7)
#define K5(X) X(0) X(1) X(2) X(3) X(4)

__attribute__((amdgpu_waves_per_eu(2, 2)))   // 2 waves/EU -> 256-reg budget
__global__ void __launch_bounds__(512)
kan_seq(const float* __restrict__ x,
        const float* __restrict__ coef1,
        const float* __restrict__ sb1,
        const float* __restrict__ sp1,
        const float* __restrict__ coef2,
        const float* __restrict__ sb2,
        const float* __restrict__ sp2,
        float* __restrict__ out)
{
    // per-wave feature scratch: 20 records x 16B (wave-local, NO barrier needed)
    __shared__ __align__(16) unsigned int scr[8][20][4];
    // double-buffered partials: [buf][0..7 = MFMA wave-partials, 8..15 = base partials][o]
    __shared__ __align__(16) float part[2][16][NHID];
    __shared__ float Hf[NHID][9];                        // epilogue h-features

    const int tid  = threadIdx.x;
    const int b    = blockIdx.x;      // one batch row per block
    const int lane = tid & 63;
    const int w    = tid >> 6;        // wave 0..7: owns records w*20 .. w*20+19
    const int arow = lane & 15;       // A-frag m index
    const int agrp = lane >> 4;       // record-within-K-tile (0..3)
    const int rec20 = w * 20 + lane;  // record owned by this lane (if lane<20)

    // ---- one-time: A-fragments (weights) -> 40 NAMED uint4 regs, sp1 folded ----
    // A-frag (kk, ot): lane holds coef1[rec][o][0..8)*sp1[rec][o] packed bf16,
    // rec = (w*5+kk)*4 + agrp, o = ot*16 + arow. Verified PASS in round 3.
#define DECLW(k) uint4 wf##k##_0, wf##k##_1, wf##k##_2, wf##k##_3, \
                       wf##k##_4, wf##k##_5, wf##k##_6, wf##k##_7;
    K5(DECLW)
#undef DECLW

#define INITW1(k,t) { \
    int rec = (w * 5 + (k)) * 4 + agrp; \
    int oo  = (t) * 16 + arow; \
    const float4* cp = (const float4*)(coef1 + (size_t)(rec * NHID + oo) * 8); \
    float sp = sp1[rec * NHID + oo]; \
    float4 c0 = cp[0], c1 = cp[1]; \
    wf##k##_##t = make_uint4(packbf(sp * c0.x, sp * c0.y), packbf(sp * c0.z, sp * c0.w), \
                             packbf(sp * c1.x, sp * c1.y), packbf(sp * c1.z, sp * c1.w)); }
#define INITWK(k) INITW1(k,0) INITW1(k,1) INITW1(k,2) INITW1(k,3) \
                  INITW1(k,4) INITW1(k,5) INITW1(k,6) INITW1(k,7)
    K5(INITWK)
#undef INITWK
#undef INITW1

    // base-term weights: record i = w*20+p, outputs (lane, lane+64) packed per reg
#define DECLSB(p) unsigned int sbp##p;
    R20(DECLSB)
#undef DECLSB
#define INITSB(p) { int i = w * 20 + (p); \
    sbp##p = packbf(sb1[i * NHID + lane], sb1[i * NHID + lane + 64]); }
    R20(INITSB)
#undef INITSB

    // h0 = 0: zero both part buffers (2*16*128 = 4096 floats)
    #pragma unroll
    for (int z = 0; z < 8; ++z) ((float*)part)[tid + 512 * z] = 0.f;
    float xv = 0.f;
    if (lane < 20 && rec20 < NIN) xv = x[(size_t)b * SEQT * NIN + rec20];
    __syncthreads();

    for (int t = 0; t < SEQT; ++t) {
        const int rb = t & 1, wb = rb ^ 1;

        // ---- phase 1 (wave-local): lanes 0..19 compute own records' features ----
        float xv_use = xv;
        if (lane < 20 && rec20 < NIN) {   // issue next-t prefetch EARLY (vmcnt drain
            int tn = (t + 1 < SEQT) ? (t + 1) : t;   //  at barrier becomes free)
            xv = x[((size_t)b * SEQT + tn) * NIN + rec20];
        }
        float silu_f = 0.f;
        if (lane < 20) {
            float c;
            if (rec20 < NIN) c = xv_use;
            else {
                int hi = rec20 - NIN;
                float s0 = (part[rb][0][hi] + part[rb][1][hi]) + (part[rb][2][hi] + part[rb][3][hi]);
                float s1 = (part[rb][4][hi] + part[rb][5][hi]) + (part[rb][6][hi] + part[rb][7][hi]);
                float s2 = (part[rb][8][hi] + part[rb][9][hi]) + (part[rb][10][hi] + part[rb][11][hi]);
                float s3 = (part[rb][12][hi] + part[rb][13][hi]) + (part[rb][14][hi] + part[rb][15][hi]);
                c = (s0 + s1) + (s2 + s3);
            }
            silu_f = fsilu(c);
            float b4[4]; int js;
            spline_feat(c, b4, &js);
            float e[8];
            #pragma unroll
            for (int k = 0; k < 8; ++k) {
                int d = k - js;
                e[k] = (d >= 0 && d < 4) ? b4[d] : 0.f;
            }
            uint4 pk;
            pk.x = packbf(e[0], e[1]); pk.y = packbf(e[2], e[3]);
            pk.z = packbf(e[4], e[5]); pk.w = packbf(e[6], e[7]);
            *(uint4*)&scr[w][lane][0] = pk;
        }

        // ---- base dot, first half (covers scratch-write drain) ----
        float bc_a = 0.f, bc_b = 0.f;
#define DOTB(p) { \
        float sb_lo = __uint_as_float(sbp##p << 16); \
        float sb_hi = __uint_as_float(sbp##p & 0xffff0000u); \
        float slr = __int_as_float(__builtin_amdgcn_readlane(__float_as_int(silu_f), (p))); \
        bc_a = __builtin_fmaf(slr, sb_lo, bc_a); \
        bc_b = __builtin_fmaf(slr, sb_hi, bc_b); }
        R10A(DOTB)

        // ---- wave-local visibility: drain LDS, then read own B-frags ----
        asm volatile("s_waitcnt lgkmcnt(0)" ::: "memory");
        __builtin_amdgcn_sched_barrier(0);
        uint4 bq0 = *(const uint4*)&scr[w][agrp][0];
        uint4 bq1 = *(const uint4*)&scr[w][4 + agrp][0];

        // ---- base dot, second half (covers B-frag read latency) ----
        R10B(DOTB)
#undef DOTB
        part[wb][8 + w][lane] = bc_a;
        part[wb][8 + w][lane + 64] = bc_b;

        // ---- 40 MFMAs (5 K-tiles x 8 o-tiles), weights resident, staged reads ----
        f32x4 ac0 = {0.f,0.f,0.f,0.f}, ac1 = {0.f,0.f,0.f,0.f},
              ac2 = {0.f,0.f,0.f,0.f}, ac3 = {0.f,0.f,0.f,0.f},
              ac4 = {0.f,0.f,0.f,0.f}, ac5 = {0.f,0.f,0.f,0.f},
              ac6 = {0.f,0.f,0.f,0.f}, ac7 = {0.f,0.f,0.f,0.f};
#define MMROW(k, bqv) { s16x8 bb_ = __builtin_bit_cast(s16x8, bqv); \
        ac0 = __builtin_amdgcn_mfma_f32_16x16x32_bf16(__builtin_bit_cast(s16x8, wf##k##_0), bb_, ac0, 0, 0, 0); \
        ac1 = __builtin_amdgcn_mfma_f32_16x16x32_bf16(__builtin_bit_cast(s16x8, wf##k##_1), bb_, ac1, 0, 0, 0); \
        ac2 = __builtin_amdgcn_mfma_f32_16x16x32_bf16(__builtin_bit_cast(s16x8, wf##k##_2), bb_, ac2, 0, 0, 0); \
        ac3 = __builtin_amdgcn_mfma_f32_16x16x32_bf16(__builtin_bit_cast(s16x8, wf##k##_3), bb_, ac3, 0, 0, 0); \
        ac4 = __builtin_amdgcn_mfma_f32_16x16x32_bf16(__builtin_bit_cast(s16x8, wf##k##_4), bb_, ac4, 0, 0, 0); \
        ac5 = __builtin_amdgcn_mfma_f32_16x16x32_bf16(__builtin_bit_cast(s16x8, wf##k##_5), bb_, ac5, 0, 0, 0); \
        ac6 = __builtin_amdgcn_mfma_f32_16x16x32_bf16(__builtin_bit_cast(s16x8, wf##k##_6), bb_, ac6, 0, 0, 0); \
        ac7 = __builtin_amdgcn_mfma_f32_16x16x32_bf16(__builtin_bit_cast(s16x8, wf##k##_7), bb_, ac7, 0, 0, 0); }
        MMROW(0, bq0)  uint4 bq2 = *(const uint4*)&scr[w][8 + agrp][0];
        MMROW(1, bq1)  uint4 bq3 = *(const uint4*)&scr[w][12 + agrp][0];
        MMROW(2, bq2)  uint4 bq4 = *(const uint4*)&scr[w][16 + agrp][0];
        MMROW(3, bq3)
        MMROW(4, bq4)
#undef MMROW

        // ---- write MFMA partials: D[m=(lane>>4)*4+j][n=lane&15]; lanes n==tt
        //      store tile tt rows (verified mapping, round 3 PASS) ----
#define WRR(tt) if ((lane & 15) == (tt)) \
            *(f32x4*)&part[wb][w][(tt) * 16 + (agrp << 2)] = ac##tt;
        O8(WRR)
#undef WRR
        __syncthreads();   // the ONE barrier: part[wb] ready for t+1
    }

    // ---- layer 2 on final h only (SEQT even -> final partials in part[0]) ----
    if (tid < NHID) {
        float s0 = (part[0][0][tid] + part[0][1][tid]) + (part[0][2][tid] + part[0][3][tid]);
        float s1 = (part[0][4][tid] + part[0][5][tid]) + (part[0][6][tid] + part[0][7][tid]);
        float s2 = (part[0][8][tid] + part[0][9][tid]) + (part[0][10][tid] + part[0][11][tid]);
        float s3 = (part[0][12][tid] + part[0][13][tid]) + (part[0][14][tid] + part[0][15][tid]);
        float c = (s0 + s1) + (s2 + s3);
        float sil = fsilu(c);
        float b4[4]; int js;
        spline_feat(c, b4, &js);
        #pragma unroll
        for (int k = 0; k < 8; ++k) {
            int d = k - js;
            Hf[tid][k] = (d >= 0 && d < 4) ? b4[d] : 0.f;
        }
        Hf[tid][8] = sil;
    }
    __syncthreads();
    if (tid < 128) {
        int o2 = tid & 15, isg = tid >> 4;     // 8 i-groups of 16
        float acc = 0.f;
        for (int q = 0; q < 16; ++q) {
            int i = isg * 16 + q;
            const float* c2 = coef2 + (size_t)(i * NOUT + o2) * 8;
            float s = 0.f;
            #pragma unroll
            for (int k = 0; k < 8; ++k) s += Hf[i][k] * c2[k];
            acc += Hf[i][8] * sb2[i * NOUT + o2] + sp2[i * NOUT + o2] * s;
        }
        ((float*)part)[isg * 16 + o2] = acc;
    }
    __syncthreads();
    if (tid < NOUT) {
        float a = 0.f;
        #pragma unroll
        for (int g = 0; g < 8; ++g) a += ((float*)part)[g * 16 + tid];
        out[(size_t)b * NOUT + tid] = a;
    }
}

extern "C" void kernel_launch(void* const* d_in, const int* in_sizes, int n_in,
                              void* d_out, int out_size, void* d_ws, size_t ws_size,
                              hipStream_t stream) {
    kan_seq<<<NB, 512, 0, stream>>>(
        (const float*)d_in[0], (const float*)d_in[1], (const float*)d_in[2],
        (const float*)d_in[3], (const float*)d_in[4], (const float*)d_in[5],
        (const float*)d_in[6], (float*)d_out);
}

// Round 5
// 978.963 us; speedup vs baseline: 1.0932x; 1.0932x over previous
//
#include <hip/hip_runtime.h>
#include <hip/hip_bf16.h>

#define NIN 32
#define NHID 128
#define NOUT 16
#define SEQT 512
#define NB 256

typedef __attribute__((ext_vector_type(8))) short s16x8;   // 8 bf16 (4 VGPRs) - MFMA A/B frag
typedef __attribute__((ext_vector_type(4))) float f32x4;   // MFMA C/D frag

// manual RNE f32->bf16 (inputs are finite/sane here)
__device__ __forceinline__ unsigned int f2bfbits(float f) {
    unsigned int u = __float_as_uint(f);
    return (u + 0x7fffu + ((u >> 16) & 1u)) >> 16;
}
__device__ __forceinline__ unsigned int packbf(float lo, float hi) {
    return f2bfbits(lo) | (f2bfbits(hi) << 16);
}

// Knots: t_m = -8.8 + 1.6*m (G=5, K=3, range [-4,4]); uniform -> closed-form
// cubic basis (verified PASS rounds 1,3,4).
__device__ __forceinline__ void spline_feat(float c, float* out4, int* jst) {
    const float t0 = -8.8f, inv_h = 0.625f;
    float u  = (c - t0) * inv_h;
    float uf = floorf(u);
    int   m0 = (int)uf;
    bool valid = (m0 >= 0) && (m0 <= 10);
    float f   = u - uf;
    float omf = 1.0f - f;
    float f2 = f * f, f3 = f2 * f;
    float omf3 = omf * omf * omf;
    const float c6 = 0.16666667f;
    float v0 = omf3 * c6;
    float v1 = __builtin_fmaf(3.0f, f3, __builtin_fmaf(-6.0f, f2, 4.0f)) * c6;
    float v2 = __builtin_fmaf(-3.0f, f3, __builtin_fmaf(3.0f, f + f2, 1.0f)) * c6;
    float v3 = f3 * c6;
    float v[4] = {v0, v1, v2, v3};
    int jb = m0 - 3;
    int js = jb < 0 ? 0 : (jb > 4 ? 4 : jb);
    int sh = js - jb;
    #pragma unroll
    for (int r = 0; r < 4; ++r) {
        int rs = r + sh;
        out4[r] = (valid && rs >= 0 && rs <= 3) ? v[rs] : 0.f;
    }
    *jst = js;
}

__device__ __forceinline__ float fsilu(float c) {
    return c * __builtin_amdgcn_rcpf(1.f + __expf(-c));
}

// sb1 with K-pad guard (always-in-bounds address; zero for padded slots k20>=20)
__device__ __forceinline__ float sb1_pad(const float* __restrict__ sb1, int w, int k20, int oo) {
    int kk = (k20 < 20) ? k20 : 0;
    float v = sb1[(w * 20 + kk) * NHID + oo];
    return (k20 < 20) ? v : 0.f;
}

// ---- X-macro lists ----
#define O8(X) X(0) X(1) X(2) X(3) X(4) X(5) X(6) X(7)
#define K5(X) X(0) X(1) X(2) X(3) X(4)
#define K6(X) X(0) X(1) X(2) X(3) X(4) X(5)

__attribute__((amdgpu_waves_per_eu(2, 2)))   // 2 waves/EU -> 256-reg budget
__global__ void __launch_bounds__(512)
kan_seq(const float* __restrict__ x,
        const float* __restrict__ coef1,
        const float* __restrict__ sb1,
        const float* __restrict__ sp1,
        const float* __restrict__ coef2,
        const float* __restrict__ sb2,
        const float* __restrict__ sp2,
        float* __restrict__ out)
{
    // per-wave feature scratch: 20 records x 16B (wave-local, NO barrier needed)
    __shared__ __align__(16) unsigned int scr[8][20][4];
    // per-wave silu K-tile: 32 bf16 slots, slots 20..31 stay zero forever
    __shared__ __align__(16) unsigned short scrS[8][32];
    // double-buffered MFMA wave-partials (base term now folded into MFMA)
    __shared__ __align__(16) float part[2][8][NHID];
    __shared__ float Hf[NHID][9];                        // epilogue h-features

    const int tid  = threadIdx.x;
    const int b    = blockIdx.x;      // one batch row per block
    const int lane = tid & 63;
    const int w    = tid >> 6;        // wave 0..7: owns records w*20 .. w*20+19
    const int arow = lane & 15;       // A-frag m index (o within tile)
    const int agrp = lane >> 4;       // k-group (0..3)
    const int rec20 = w * 20 + lane;  // record owned by this lane (if lane<20)

    // ---- one-time: A-fragments -> 48 NAMED uint4 regs ----
    // k=0..4: spline weights sp1*coef1 (verified mapping, rounds 3-4 PASS)
    // k=5:    silu-tile weights sb1 (k-slot = record index in wave, pad>=20 -> 0)
#define DECLW(k) uint4 wf##k##_0, wf##k##_1, wf##k##_2, wf##k##_3, \
                       wf##k##_4, wf##k##_5, wf##k##_6, wf##k##_7;
    K6(DECLW)
#undef DECLW

#define INITW1(k,t) { \
    int rec = (w * 5 + (k)) * 4 + agrp; \
    int oo  = (t) * 16 + arow; \
    const float4* cp = (const float4*)(coef1 + (size_t)(rec * NHID + oo) * 8); \
    float sp = sp1[rec * NHID + oo]; \
    float4 c0 = cp[0], c1 = cp[1]; \
    wf##k##_##t = make_uint4(packbf(sp * c0.x, sp * c0.y), packbf(sp * c0.z, sp * c0.w), \
                             packbf(sp * c1.x, sp * c1.y), packbf(sp * c1.z, sp * c1.w)); }
#define INITWK(k) INITW1(k,0) INITW1(k,1) INITW1(k,2) INITW1(k,3) \
                  INITW1(k,4) INITW1(k,5) INITW1(k,6) INITW1(k,7)
    K5(INITWK)
#undef INITWK
#undef INITW1

#define INITW5(t) { \
    int oo = (t) * 16 + arow; \
    int kb = agrp * 8; \
    float e0 = sb1_pad(sb1, w, kb + 0, oo), e1 = sb1_pad(sb1, w, kb + 1, oo); \
    float e2 = sb1_pad(sb1, w, kb + 2, oo), e3 = sb1_pad(sb1, w, kb + 3, oo); \
    float e4 = sb1_pad(sb1, w, kb + 4, oo), e5 = sb1_pad(sb1, w, kb + 5, oo); \
    float e6 = sb1_pad(sb1, w, kb + 6, oo), e7 = sb1_pad(sb1, w, kb + 7, oo); \
    wf5_##t = make_uint4(packbf(e0, e1), packbf(e2, e3), packbf(e4, e5), packbf(e6, e7)); }
    O8(INITW5)
#undef INITW5

    // h0 = 0: zero part buffers (2*8*128 = 2048 floats) and silu tiles
    #pragma unroll
    for (int z = 0; z < 4; ++z) ((float*)part)[tid + 512 * z] = 0.f;
    if (tid < 128) ((unsigned int*)scrS)[tid] = 0u;   // 8*32 ushorts = 128 uints
    float xv = 0.f;
    if (lane < 20 && rec20 < NIN) xv = x[(size_t)b * SEQT * NIN + rec20];
    const f32x4 zq = {0.f, 0.f, 0.f, 0.f};            // hoisted acc seed
    __syncthreads();

    for (int t = 0; t < SEQT; ++t) {
        const int rb = t & 1, wb = rb ^ 1;

        // ---- phase 1 (wave-local): lanes 0..19 compute own records' features ----
        float xv_use = xv;
        if (lane < 20 && rec20 < NIN) {   // early global prefetch of next x
            int tn = (t + 1 < SEQT) ? (t + 1) : t;
            xv = x[((size_t)b * SEQT + tn) * NIN + rec20];
        }
        if (lane < 20) {
            float c;
            if (rec20 < NIN) c = xv_use;
            else {
                int hi = rec20 - NIN;
                float s0 = (part[rb][0][hi] + part[rb][1][hi]) + (part[rb][2][hi] + part[rb][3][hi]);
                float s1 = (part[rb][4][hi] + part[rb][5][hi]) + (part[rb][6][hi] + part[rb][7][hi]);
                c = s0 + s1;
            }
            float sil = fsilu(c);
            float b4[4]; int js;
            spline_feat(c, b4, &js);
            float e[8];
            #pragma unroll
            for (int k = 0; k < 8; ++k) {
                int d = k - js;
                e[k] = (d >= 0 && d < 4) ? b4[d] : 0.f;
            }
            uint4 pk;
            pk.x = packbf(e[0], e[1]); pk.y = packbf(e[2], e[3]);
            pk.z = packbf(e[4], e[5]); pk.w = packbf(e[6], e[7]);
            *(uint4*)&scr[w][lane][0] = pk;
            scrS[w][lane] = (unsigned short)f2bfbits(sil);
        }

        // ---- wave-local visibility: drain LDS, then read own B-frags ----
        asm volatile("s_waitcnt lgkmcnt(0)" ::: "memory");
        __builtin_amdgcn_sched_barrier(0);
        uint4 bq0 = *(const uint4*)&scr[w][agrp][0];
        uint4 bq1 = *(const uint4*)&scr[w][4 + agrp][0];

        // ---- 48 MFMAs (5 spline K-tiles + 1 silu K-tile) x 8 o-tiles ----
        f32x4 ac0, ac1, ac2, ac3, ac4, ac5, ac6, ac7;
#define MMROW0(k, bqv) { s16x8 bb_ = __builtin_bit_cast(s16x8, bqv); \
        ac0 = __builtin_amdgcn_mfma_f32_16x16x32_bf16(__builtin_bit_cast(s16x8, wf##k##_0), bb_, zq, 0, 0, 0); \
        ac1 = __builtin_amdgcn_mfma_f32_16x16x32_bf16(__builtin_bit_cast(s16x8, wf##k##_1), bb_, zq, 0, 0, 0); \
        ac2 = __builtin_amdgcn_mfma_f32_16x16x32_bf16(__builtin_bit_cast(s16x8, wf##k##_2), bb_, zq, 0, 0, 0); \
        ac3 = __builtin_amdgcn_mfma_f32_16x16x32_bf16(__builtin_bit_cast(s16x8, wf##k##_3), bb_, zq, 0, 0, 0); \
        ac4 = __builtin_amdgcn_mfma_f32_16x16x32_bf16(__builtin_bit_cast(s16x8, wf##k##_4), bb_, zq, 0, 0, 0); \
        ac5 = __builtin_amdgcn_mfma_f32_16x16x32_bf16(__builtin_bit_cast(s16x8, wf##k##_5), bb_, zq, 0, 0, 0); \
        ac6 = __builtin_amdgcn_mfma_f32_16x16x32_bf16(__builtin_bit_cast(s16x8, wf##k##_6), bb_, zq, 0, 0, 0); \
        ac7 = __builtin_amdgcn_mfma_f32_16x16x32_bf16(__builtin_bit_cast(s16x8, wf##k##_7), bb_, zq, 0, 0, 0); }
#define MMROW(k, bqv) { s16x8 bb_ = __builtin_bit_cast(s16x8, bqv); \
        ac0 = __builtin_amdgcn_mfma_f32_16x16x32_bf16(__builtin_bit_cast(s16x8, wf##k##_0), bb_, ac0, 0, 0, 0); \
        ac1 = __builtin_amdgcn_mfma_f32_16x16x32_bf16(__builtin_bit_cast(s16x8, wf##k##_1), bb_, ac1, 0, 0, 0); \
        ac2 = __builtin_amdgcn_mfma_f32_16x16x32_bf16(__builtin_bit_cast(s16x8, wf##k##_2), bb_, ac2, 0, 0, 0); \
        ac3 = __builtin_amdgcn_mfma_f32_16x16x32_bf16(__builtin_bit_cast(s16x8, wf##k##_3), bb_, ac3, 0, 0, 0); \
        ac4 = __builtin_amdgcn_mfma_f32_16x16x32_bf16(__builtin_bit_cast(s16x8, wf##k##_4), bb_, ac4, 0, 0, 0); \
        ac5 = __builtin_amdgcn_mfma_f32_16x16x32_bf16(__builtin_bit_cast(s16x8, wf##k##_5), bb_, ac5, 0, 0, 0); \
        ac6 = __builtin_amdgcn_mfma_f32_16x16x32_bf16(__builtin_bit_cast(s16x8, wf##k##_6), bb_, ac6, 0, 0, 0); \
        ac7 = __builtin_amdgcn_mfma_f32_16x16x32_bf16(__builtin_bit_cast(s16x8, wf##k##_7), bb_, ac7, 0, 0, 0); }
        MMROW0(0, bq0)  uint4 bq2 = *(const uint4*)&scr[w][8 + agrp][0];
        MMROW(1, bq1)   uint4 bq3 = *(const uint4*)&scr[w][12 + agrp][0];
        MMROW(2, bq2)   uint4 bq4 = *(const uint4*)&scr[w][16 + agrp][0];
        MMROW(3, bq3)   uint4 bq5 = *(const uint4*)&scrS[w][agrp * 8];
        MMROW(4, bq4)
        MMROW(5, bq5)
#undef MMROW
#undef MMROW0

        // ---- write MFMA partials: lane holds D[m=agrp*4+j][n=arow]; lanes with
        //      arow==tt store o-tile tt (verified mapping, rounds 3-4 PASS) ----
#define WRR(tt) if (arow == (tt)) \
            *(f32x4*)&part[wb][w][(tt) * 16 + (agrp << 2)] = ac##tt;
        O8(WRR)
#undef WRR
        __syncthreads();   // the ONE barrier: part[wb] ready for t+1
    }

    // ---- layer 2 on final h only (SEQT even -> final partials in part[0]) ----
    if (tid < NHID) {
        float s0 = (part[0][0][tid] + part[0][1][tid]) + (part[0][2][tid] + part[0][3][tid]);
        float s1 = (part[0][4][tid] + part[0][5][tid]) + (part[0][6][tid] + part[0][7][tid]);
        float c = s0 + s1;
        float sil = fsilu(c);
        float b4[4]; int js;
        spline_feat(c, b4, &js);
        #pragma unroll
        for (int k = 0; k < 8; ++k) {
            int d = k - js;
            Hf[tid][k] = (d >= 0 && d < 4) ? b4[d] : 0.f;
        }
        Hf[tid][8] = sil;
    }
    __syncthreads();
    if (tid < 128) {
        int o2 = tid & 15, isg = tid >> 4;     // 8 i-groups of 16
        float acc = 0.f;
        for (int q = 0; q < 16; ++q) {
            int i = isg * 16 + q;
            const float* c2 = coef2 + (size_t)(i * NOUT + o2) * 8;
            float s = 0.f;
            #pragma unroll
            for (int k = 0; k < 8; ++k) s += Hf[i][k] * c2[k];
            acc += Hf[i][8] * sb2[i * NOUT + o2] + sp2[i * NOUT + o2] * s;
        }
        ((float*)part)[isg * 16 + o2] = acc;
    }
    __syncthreads();
    if (tid < NOUT) {
        float a = 0.f;
        #pragma unroll
        for (int g = 0; g < 8; ++g) a += ((float*)part)[g * 16 + tid];
        out[(size_t)b * NOUT + tid] = a;
    }
}

extern "C" void kernel_launch(void* const* d_in, const int* in_sizes, int n_in,
                              void* d_out, int out_size, void* d_ws, size_t ws_size,
                              hipStream_t stream) {
    kan_seq<<<NB, 512, 0, stream>>>(
        (const float*)d_in[0], (const float*)d_in[1], (const float*)d_in[2],
        (const float*)d_in[3], (const float*)d_in[4], (const float*)d_in[5],
        (const float*)d_in[6], (float*)d_out);
}